// Round 14
// baseline (118.066 us; speedup 1.0000x reference)
//
#include <hip/hip_runtime.h>
#include <math.h>

// GeometricEmbedding: B=4, N=M=3000, d_model=2, sigma_d=1.0
// out[0..12000)  float2 = p0[b,n] * (sum_m sin d, sum_m cos d)
// out[12000..24000)     = p1[b,m] * (sum_n sin d, sum_n cos d)
// d = sqrt(max(2 - 2*<p0,p1>, 0)); HW sin/cos in revolutions ((1/2pi)^2
// folded into fma constants so sqrt(t) = d/2pi directly) - exact R0 math.
//
// R20: R0/R15/R19 all ~330-360 cyc/step despite wildly different V/T/LDS
// mixes -> pipe-swapping is zero-sum at ~1.2 cyc/eval; the only 2x left is
// EVAL COUNT (72e6 -> 36e6, each pair once, both outputs). Prior shared-
// eval attempts lost to machinery (LDS flush/barriers R8-R11, fat stores
// R12). Machinery-free version: wave = 8 rows x 8 cols (lane = c*8+r).
// Per step: 1 broadcast load (8 q's), 1 eval/lane, row sums in registers
// (free), col sums via 3 DPP adds (quad_perm xor1/xor2 + row_half_mirror,
// full-rate VALU, no LDS pipe, no barriers), 1 coalesced 64B store from
// 8 lanes. ~23 VALU + 3 trans per 64 shared evals vs R0's 96+12 per 256
// one-sided -> ~45% fewer issue cycles. 7500 waves, grid fully resident.
// Col partials 36MB to ws; reduce reuses R12's proven 375-deep reducer.

#define GB 4
#define GN 3000
#define RGPB 375                    // row-groups of 8 per batch
#define CCH 5                       // column chunks per batch
#define CPW 600                     // columns per wave (chunk width)
#define WPB 1875                    // waves per batch = RGPB*CCH
#define K2 0.025330295910584444f    // (1/2pi)^2
#define C2 0.050660591821168888f    // 2*(1/2pi)^2

// ws layout (float2 units):
//   [0, COLPART_F2): colpart[(b*RGPB+rg)*GN + m]  (sum over rg's 8 rows)
//   [COLPART_F2, +60000): rowpart[wid*8 + r]      (row sums over wid's 600 cols)
#define COLPART_F2 (GB*RGPB*GN)

// DPP-based xor-reduce within 8-lane groups (full-rate VALU, no LDS pipe)
__device__ __forceinline__ float dpp_add(float x, int ctrl_tag) {
    int v;
    if (ctrl_tag == 0)       // quad_perm [1,0,3,2]  : xor 1
        v = __builtin_amdgcn_update_dpp(0, __float_as_int(x), 0xB1, 0xF, 0xF, true);
    else if (ctrl_tag == 1)  // quad_perm [2,3,0,1]  : xor 2
        v = __builtin_amdgcn_update_dpp(0, __float_as_int(x), 0x4E, 0xF, 0xF, true);
    else                     // row_half_mirror      : completes 8-lane sum
        v = __builtin_amdgcn_update_dpp(0, __float_as_int(x), 0x141, 0xF, 0xF, true);
    return x + __int_as_float(v);
}
__device__ __forceinline__ float sum8(float x) {
    x = dpp_add(x, 0);
    x = dpp_add(x, 1);
    x = dpp_add(x, 2);
    return x;               // all 8 lanes of the group hold the sum
}

__global__ __launch_bounds__(256, 8) void geo_pair_kernel(
    const float* __restrict__ p0,
    const float* __restrict__ p1,
    float2* __restrict__ ws)
{
    const int lane = threadIdx.x & 63;
    const int wid  = (blockIdx.x << 2) | (threadIdx.x >> 6);  // 0..7499
    const int b    = wid / WPB;                 // magic-mul
    const int rem  = wid - b * WPB;
    const int rg   = rem / CCH;                 // row-group 0..374
    const int cc   = rem - rg * CCH;            // col chunk 0..4
    const int r    = lane & 7;                  // row within group
    const int c    = lane >> 3;                 // col within step-tile

    // per-lane row constants (8 rows, 8-way broadcast load)
    const float2 pr = ((const float2*)p0)[b * GN + (rg << 3) + r];
    const float mm  = -2.0f * K2;
    const float ax  = mm * pr.x;
    const float ay  = mm * pr.y;
    const float c2v = C2;

    const float2* __restrict__ qp = (const float2*)p1 + b * GN + cc * CPW + c;
    float2*       __restrict__ sp = ws + (b * RGPB + rg) * GN + cc * CPW + c;

    float rs = 0.f, rc = 0.f;

#define STEP(q) do {                                                     \
    float t_ = fmaf(ax, (q).x, fmaf(ay, (q).y, c2v));                    \
    t_ = fmaxf(t_, 0.f);                                                 \
    float d_ = __builtin_amdgcn_sqrtf(t_);                               \
    float sn = __builtin_amdgcn_sinf(d_);                                \
    float cs = __builtin_amdgcn_cosf(d_);                                \
    rs += sn; rc += cs;                                                  \
    float s8 = sum8(sn);                                                 \
    float c8 = sum8(cs);                                                 \
    if (r == 0) sp[0] = make_float2(s8, c8);                             \
    sp += 8;                                                             \
} while (0)

    float2 qA = qp[0];
    #pragma unroll 1
    for (int j = 0; j < 74; ++j) {              // steps 0..73
        float2 qB = qp[8];                      // prefetch next 8 cols
        qp += 8;
        STEP(qA);
        qA = qB;
    }
    STEP(qA);                                   // step 74 (cols 592..599)
#undef STEP

    // row sums: reduce over the 8 c-lanes (stride 8) - once, at the end
    #pragma unroll
    for (int off = 8; off <= 32; off <<= 1) {
        rs += __shfl_xor(rs, off, 64);
        rc += __shfl_xor(rc, off, 64);
    }
    if (lane < 8)                               // c==0 lanes: rows rg*8+0..7
        ws[COLPART_F2 + (wid << 3) + r] = make_float2(rs, rc);
}

// Reduce: side1 = 375 blocks of (32 cols x 8 k-chunks of 47) - R12's proven
// pattern, identical colpart layout. side0 = 47 blocks x 5 chunk-partials.
__global__ __launch_bounds__(256, 4) void geo_reduce_kernel(
    const float* __restrict__ p0,
    const float* __restrict__ p1,
    const float2* __restrict__ ws,
    float2* __restrict__ out)
{
    __shared__ float2 acc[8][32];
    const int blk = blockIdx.x;
    if (blk < 375) {
        const int cc = threadIdx.x & 31;        // column within group
        const int kc = threadIdx.x >> 5;        // k-chunk 0..7
        const int g  = blk * 32 + cc;           // flat (b,m): 0..11999
        const int b  = g / GN;                  // magic-mul
        const int m  = g - b * GN;
        const float2* __restrict__ base = ws + b * (RGPB * GN) + m;
        const int k0 = kc * 47;
        float sv = 0.f, cv = 0.f;
        #pragma unroll
        for (int j = 0; j < 47; ++j) {          // kc==7: k=375 guarded out
            const int k = k0 + j;
            if (k < RGPB) {
                float2 v = base[k * GN];
                sv += v.x; cv += v.y;
            }
        }
        acc[kc][cc] = make_float2(sv, cv);
        __syncthreads();
        if (kc == 0) {
            float2 rr = acc[0][cc];
            #pragma unroll
            for (int j = 1; j < 8; ++j) { rr.x += acc[j][cc].x; rr.y += acc[j][cc].y; }
            const float2 p = ((const float2*)p1)[g];
            out[GB * GN + g] = make_float2(p.x * rr.x, p.y * rr.y);
        }
    } else {
        const int idx = (blk - 375) * 256 + threadIdx.x;   // 0..12031
        if (idx < GB * GN) {
            const int b = idx / GN;             // magic-mul
            const int n = idx - b * GN;
            const int rg = n >> 3;
            const int r  = n & 7;
            const int wid0 = b * WPB + rg * CCH;
            float sv = 0.f, cv = 0.f;
            #pragma unroll
            for (int cc = 0; cc < CCH; ++cc) {
                float2 v = ws[COLPART_F2 + ((wid0 + cc) << 3) + r];
                sv += v.x; cv += v.y;
            }
            const float2 p = ((const float2*)p0)[idx];
            out[idx] = make_float2(p.x * sv, p.y * cv);
        }
    }
}

extern "C" void kernel_launch(void* const* d_in, const int* in_sizes, int n_in,
                              void* d_out, int out_size, void* d_ws, size_t ws_size,
                              hipStream_t stream) {
    const float* points0 = (const float*)d_in[0];
    const float* points1 = (const float*)d_in[1];

    // ws usage: (4*375*3000 + 60000) float2 ~= 36.5 MB
    geo_pair_kernel<<<dim3(WPB), dim3(256), 0, stream>>>(
        points0, points1, (float2*)d_ws);
    geo_reduce_kernel<<<dim3(375 + 47), dim3(256), 0, stream>>>(
        points0, points1, (const float2*)d_ws, (float2*)d_out);
}

// Round 15
// 86.914 us; speedup vs baseline: 1.3584x; 1.3584x over previous
//
#include <hip/hip_runtime.h>
#include <math.h>

// GeometricEmbedding: B=4, N=M=3000, d_model=2, sigma_d=1.0
// out[0..12000)  float2 = p0[b,n] * (sum_m sin d, sum_m cos d)
// out[12000..24000)     = p1[b,m] * (sum_n sin d, sum_n cos d)
// d = sqrt(max(2 - 2*<p0,p1>, 0)); HW sin/cos in revolutions ((1/2pi)^2
// folded into fma constants so sqrt(t) = d/2pi) - exact R0 math.
//
// R21: R20 (shared-eval, 45.4us, VALUBusy 41%) was ILP-starved: ONE dep
// chain per step + per-step masked 64B store. Fix, keeping the halved eval
// count: wave = 24 rows x 8 cols (3 row-sets of 8; 3000=125*24, =15*200,
// zero tails). Per octet 3 independent eval chains pre-added before ONE
// sum8 pair (DPP cost amortized 3x); 5 octets unrolled/iter = 5 chains in
// flight (>= R0's 4); col sums held in regs (r==k cndmask) and flushed as
// one contiguous 320B store per 40 cols. Colpart traffic 36->12MB.
// Budget ~34V+9T per 192 pairs ~= 1.5 cyc/pair -> pair ~24-30us.
// Falsifier (pre-committed): pair >= 35us -> shared-eval closed, R15 is
// the pragmatic ceiling.

#define GB 4
#define GN 3000
#define RPW 24                      // rows per wave (3 sets of 8)
#define RG  125                     // row groups per batch (3000/24)
#define CCH 15                      // col chunks per batch
#define CPW 200                     // cols per wave (5 iters x 5 octets x 8)
#define WPB (RG*CCH)                // 1875 waves per batch
#define K2 0.025330295910584444f    // (1/2pi)^2
#define C2 0.050660591821168888f    // 2*(1/2pi)^2

// ws layout (float2 units):
//   [0, COLPART_F2): colpart[(b*RG+rg)*GN + m]  (sum over rg's 24 rows)
//   [COLPART_F2, +180000): rowpart[wid*24 + q]  (row sums over wid's 200 cols)
#define COLPART_F2 (GB*RG*GN)

// 8-consecutive-lane sum via full-rate DPP (R20-proven, absmax 0.0):
// quad_perm xor1, xor2, then row_half_mirror (xor4 within 8).
__device__ __forceinline__ float dpp_add(float x, int tag) {
    int v;
    if (tag == 0)
        v = __builtin_amdgcn_update_dpp(0, __float_as_int(x), 0xB1, 0xF, 0xF, true);
    else if (tag == 1)
        v = __builtin_amdgcn_update_dpp(0, __float_as_int(x), 0x4E, 0xF, 0xF, true);
    else
        v = __builtin_amdgcn_update_dpp(0, __float_as_int(x), 0x141, 0xF, 0xF, true);
    return x + __int_as_float(v);
}
__device__ __forceinline__ float sum8(float x) {
    x = dpp_add(x, 0);
    x = dpp_add(x, 1);
    x = dpp_add(x, 2);
    return x;               // all 8 lanes of the group hold the sum
}

__global__ __launch_bounds__(256, 8) void geo_pair_kernel(
    const float* __restrict__ p0,
    const float* __restrict__ p1,
    float2* __restrict__ ws)
{
    const int lane = threadIdx.x & 63;
    const int wid  = (blockIdx.x << 2) | (threadIdx.x >> 6);  // 0..7499
    const int b    = wid / WPB;                 // magic-mul
    const int rem  = wid - b * WPB;
    const int rg   = rem / CCH;                 // row-group 0..124
    const int cc   = rem - rg * CCH;            // col chunk 0..14
    const int r    = lane & 7;                  // row-in-set / octet slot
    const int c    = lane >> 3;                 // col within octet

    // row constants: rows rg*24 + r + 8s, s=0..2 (8-way broadcast loads)
    const float2* __restrict__ prp = (const float2*)p0 + b * GN + rg * RPW + r;
    const float mm = -2.0f * K2;
    const float2 pA = prp[0], pB = prp[8], pC = prp[16];
    const float ax0 = mm * pA.x, ay0 = mm * pA.y;
    const float ax1 = mm * pB.x, ay1 = mm * pB.y;
    const float ax2 = mm * pC.x, ay2 = mm * pC.y;
    const float c2v = C2;

    const float2* __restrict__ qp = (const float2*)p1 + b * GN + cc * CPW + c;
    float2*       __restrict__ spc = ws + (b * RG + rg) * GN + cc * CPW;
    const int colw = (r << 3) | c;              // col offset this lane stores

    float rs0=0.f, rc0=0.f, rs1=0.f, rc1=0.f, rs2=0.f, rc2=0.f;

    // one octet: 8 cols x 24 rows = 192 evals; 3 independent chains, then
    // one sum8 pair; hold the octet's col-sum in the r==k lane slot.
#define OCTET(q, k) do {                                                 \
    float t0 = fmaf(ax0, (q).x, fmaf(ay0, (q).y, c2v));                  \
    float t1 = fmaf(ax1, (q).x, fmaf(ay1, (q).y, c2v));                  \
    float t2 = fmaf(ax2, (q).x, fmaf(ay2, (q).y, c2v));                  \
    t0 = fmaxf(t0, 0.f); t1 = fmaxf(t1, 0.f); t2 = fmaxf(t2, 0.f);       \
    float d0 = __builtin_amdgcn_sqrtf(t0);                               \
    float d1 = __builtin_amdgcn_sqrtf(t1);                               \
    float d2 = __builtin_amdgcn_sqrtf(t2);                               \
    float sn0 = __builtin_amdgcn_sinf(d0), cs0 = __builtin_amdgcn_cosf(d0); \
    float sn1 = __builtin_amdgcn_sinf(d1), cs1 = __builtin_amdgcn_cosf(d1); \
    float sn2 = __builtin_amdgcn_sinf(d2), cs2 = __builtin_amdgcn_cosf(d2); \
    rs0 += sn0; rc0 += cs0; rs1 += sn1; rc1 += cs1; rs2 += sn2; rc2 += cs2; \
    float ss = (sn0 + sn1) + sn2;                                        \
    float sc = (cs0 + cs1) + cs2;                                        \
    ss = sum8(ss); sc = sum8(sc);                                        \
    hs = (r == (k)) ? ss : hs;                                           \
    hc = (r == (k)) ? sc : hc;                                           \
} while (0)

    #pragma unroll 1
    for (int it = 0; it < 5; ++it) {            // 5 iters x 40 cols
        float2 q0 = qp[0],  q1 = qp[8],  q2 = qp[16];
        float2 q3 = qp[24], q4 = qp[32];
        qp += 40;
        float hs = 0.f, hc = 0.f;
        OCTET(q0, 0); OCTET(q1, 1); OCTET(q2, 2); OCTET(q3, 3); OCTET(q4, 4);
        if (r < 5)                              // 40 lanes, 320B contiguous
            spc[colw] = make_float2(hs, hc);
        spc += 40;
    }
#undef OCTET

    // row sums: reduce over the 8 c-lanes (stride 8), end-of-kernel only
    #pragma unroll
    for (int off = 8; off <= 32; off <<= 1) {
        rs0 += __shfl_xor(rs0, off, 64);  rc0 += __shfl_xor(rc0, off, 64);
        rs1 += __shfl_xor(rs1, off, 64);  rc1 += __shfl_xor(rc1, off, 64);
        rs2 += __shfl_xor(rs2, off, 64);  rc2 += __shfl_xor(rc2, off, 64);
    }
    if (c == 0) {                               // lanes 0..7: rows r+8s
        float2* rp = ws + COLPART_F2 + wid * RPW + r;
        rp[0]  = make_float2(rs0, rc0);
        rp[8]  = make_float2(rs1, rc1);
        rp[16] = make_float2(rs2, rc2);
    }
}

// Reduce: side1 = 375 blocks of (32 cols x 8 k-chunks of 16) over 125
// partials (R12-proven pattern). side0 = 47 blocks x 15 chunk-partials.
__global__ __launch_bounds__(256, 4) void geo_reduce_kernel(
    const float* __restrict__ p0,
    const float* __restrict__ p1,
    const float2* __restrict__ ws,
    float2* __restrict__ out)
{
    __shared__ float2 acc[8][32];
    const int blk = blockIdx.x;
    if (blk < 375) {
        const int cl = threadIdx.x & 31;        // column within group
        const int kc = threadIdx.x >> 5;        // k-chunk 0..7
        const int g  = blk * 32 + cl;           // flat (b,m): 0..11999
        const int b  = g / GN;                  // magic-mul
        const int m  = g - b * GN;
        const float2* __restrict__ base = ws + b * (RG * GN) + m;
        const int k0 = kc * 16;
        float sv = 0.f, cv = 0.f;
        #pragma unroll
        for (int j = 0; j < 16; ++j) {
            const int k = k0 + j;
            if (k < RG) {
                float2 v = base[k * GN];
                sv += v.x; cv += v.y;
            }
        }
        acc[kc][cl] = make_float2(sv, cv);
        __syncthreads();
        if (kc == 0) {
            float2 rr = acc[0][cl];
            #pragma unroll
            for (int j = 1; j < 8; ++j) { rr.x += acc[j][cl].x; rr.y += acc[j][cl].y; }
            const float2 p = ((const float2*)p1)[g];
            out[GB * GN + g] = make_float2(p.x * rr.x, p.y * rr.y);
        }
    } else {
        const int idx = (blk - 375) * 256 + threadIdx.x;   // 0..12031
        if (idx < GB * GN) {
            const int b  = idx / GN;            // magic-mul
            const int n  = idx - b * GN;
            const int rg = n / RPW;
            const int q  = n - rg * RPW;
            const int wid0 = (b * RG + rg) * CCH;
            const float2* __restrict__ rp = ws + COLPART_F2 + wid0 * RPW + q;
            float sv = 0.f, cv = 0.f;
            #pragma unroll
            for (int cc = 0; cc < CCH; ++cc) {
                float2 v = rp[cc * RPW];
                sv += v.x; cv += v.y;
            }
            const float2 p = ((const float2*)p0)[idx];
            out[idx] = make_float2(p.x * sv, p.y * cv);
        }
    }
}

extern "C" void kernel_launch(void* const* d_in, const int* in_sizes, int n_in,
                              void* d_out, int out_size, void* d_ws, size_t ws_size,
                              hipStream_t stream) {
    const float* points0 = (const float*)d_in[0];
    const float* points1 = (const float*)d_in[1];

    // ws usage: (4*125*3000 + 180000) float2 ~= 13.4 MB
    geo_pair_kernel<<<dim3(WPB), dim3(256), 0, stream>>>(
        points0, points1, (float2*)d_ws);
    geo_reduce_kernel<<<dim3(375 + 47), dim3(256), 0, stream>>>(
        points0, points1, (const float2*)d_ws, (float2*)d_out);
}

// Round 16
// 79.821 us; speedup vs baseline: 1.4791x; 1.0889x over previous
//
#include <hip/hip_runtime.h>
#include <math.h>

// GeometricEmbedding: B=4, N=M=3000, d_model=2, sigma_d=1.0
// out[0..12000) float2 = p0[i] * (sum_m sin d, sum_m cos d)
// out[12000..24000)    = p1[i] * (sum_n sin d, sum_n cos d)
// d = sqrt(max(2 - 2*<p0,p1>, 0))
//
// R22 == R0 kernel restored (best proven: 79.56us this session, absmax 0).
// CLOSURE NOTE (R0-R21): 12 structures all land at ~2.7 cyc/pair:
//   - pipe swaps are zero-sum: LDS tables (R15/16), scalar Chebyshev (R19),
//     pk-f32 (R12, worse: half-rate on gfx950) all == R0's pure-trans;
//   - eval-halving (R7-R12, R20/R21) loses its 2x to flush/ILP machinery
//     (3 independent implementations, incl. machinery-free DPP shared-eval);
//   - occupancy 2x (R17): no change -> throughput-bound, not latency;
//   - random LDS gather ~40-50cyc regardless of width (R15 vs R16).
// Ceiling: 72e6 x {2fma,clamp,sqrt,sin,cos}, trans ~24 eff cyc/wave-instr
// -> ~37us kernel + ~40-44us fixed harness poison-fill = ~78-81us total.

#define GB 4
#define GN 3000
#define K2 0.025330295910584444f    // (1/2pi)^2
#define C2 0.050660591821168888f    // 2*(1/2pi)^2

__device__ __forceinline__ float sreg(float x) {   // pin wave-uniform to SGPR
    return __int_as_float(__builtin_amdgcn_readfirstlane(__float_as_int(x)));
}

__global__ __launch_bounds__(256, 4) void geo_emb_kernel(
    const float* __restrict__ p0,
    const float* __restrict__ p1,
    float* __restrict__ out)
{
    const int lane = threadIdx.x & 63;
    const int wid  = (blockIdx.x << 2) | (threadIdx.x >> 6);  // 0..5999 quads

    const bool side0 = (wid < 3000);
    const int quad = side0 ? wid : wid - 3000;
    const int i2   = quad << 2;               // first row (0..11996), 4 | GN
    const int b    = i2 / GN;                 // magic-mul

    const float2* __restrict__ ownp = (const float2*)(side0 ? p0 : p1);
    const float2* __restrict__ othp = (const float2*)(side0 ? p1 : p0);

    const float2 pr0 = ownp[i2 + 0];
    const float2 pr1 = ownp[i2 + 1];
    const float2 pr2 = ownp[i2 + 2];
    const float2 pr3 = ownp[i2 + 3];

    const float mm = -2.0f * K2;
    const float ax0 = sreg(mm * pr0.x), ay0 = sreg(mm * pr0.y);
    const float ax1 = sreg(mm * pr1.x), ay1 = sreg(mm * pr1.y);
    const float ax2 = sreg(mm * pr2.x), ay2 = sreg(mm * pr2.y);
    const float ax3 = sreg(mm * pr3.x), ay3 = sreg(mm * pr3.y);
    const float c2v = C2;

    float s0 = 0.f, c0 = 0.f, s1 = 0.f, c1 = 0.f;
    float s2 = 0.f, c2 = 0.f, s3 = 0.f, c3 = 0.f;

#define STEP(q) do {                                                     \
    float t0 = fmaf(ax0, (q).x, fmaf(ay0, (q).y, c2v));                  \
    float t1 = fmaf(ax1, (q).x, fmaf(ay1, (q).y, c2v));                  \
    float t2 = fmaf(ax2, (q).x, fmaf(ay2, (q).y, c2v));                  \
    float t3 = fmaf(ax3, (q).x, fmaf(ay3, (q).y, c2v));                  \
    t0 = fmaxf(t0, 0.f); t1 = fmaxf(t1, 0.f);                            \
    t2 = fmaxf(t2, 0.f); t3 = fmaxf(t3, 0.f);                            \
    float r0 = __builtin_amdgcn_sqrtf(t0);                               \
    float r1 = __builtin_amdgcn_sqrtf(t1);                               \
    float r2 = __builtin_amdgcn_sqrtf(t2);                               \
    float r3 = __builtin_amdgcn_sqrtf(t3);                               \
    s0 += __builtin_amdgcn_sinf(r0); c0 += __builtin_amdgcn_cosf(r0);    \
    s1 += __builtin_amdgcn_sinf(r1); c1 += __builtin_amdgcn_cosf(r1);    \
    s2 += __builtin_amdgcn_sinf(r2); c2 += __builtin_amdgcn_cosf(r2);    \
    s3 += __builtin_amdgcn_sinf(r3); c3 += __builtin_amdgcn_cosf(r3);    \
} while (0)

    const float2* __restrict__ qp = othp + b * GN + lane;
    float2 qA = qp[0];
    #pragma unroll 1
    for (int j = 0; j < 45; ++j) {        // compute cols lane + {0..44}*64
        float2 qB = qp[64];
        qp += 64;
        STEP(qA);
        qA = qB;
    }
    STEP(qA);                             // col lane + 45*64   (2944 total)
    if (lane < 56) {                      // cols 2944..2999
        float2 qT = qp[64];
        STEP(qT);
    }
#undef STEP

    #pragma unroll
    for (int off = 32; off >= 1; off >>= 1) {
        s0 += __shfl_down(s0, off, 64);  c0 += __shfl_down(c0, off, 64);
        s1 += __shfl_down(s1, off, 64);  c1 += __shfl_down(c1, off, 64);
        s2 += __shfl_down(s2, off, 64);  c2 += __shfl_down(c2, off, 64);
        s3 += __shfl_down(s3, off, 64);  c3 += __shfl_down(c3, off, 64);
    }

    if (lane == 0) {
        float2* o2 = (float2*)out;
        const int ob = wid << 2;          // side1 quads land at 12000+
        o2[ob + 0] = make_float2(pr0.x * s0, pr0.y * c0);
        o2[ob + 1] = make_float2(pr1.x * s1, pr1.y * c1);
        o2[ob + 2] = make_float2(pr2.x * s2, pr2.y * c2);
        o2[ob + 3] = make_float2(pr3.x * s3, pr3.y * c3);
    }
}

extern "C" void kernel_launch(void* const* d_in, const int* in_sizes, int n_in,
                              void* d_out, int out_size, void* d_ws, size_t ws_size,
                              hipStream_t stream) {
    const float* points0 = (const float*)d_in[0];
    const float* points1 = (const float*)d_in[1];
    float* out = (float*)d_out;

    dim3 grid(1500);    // 6000 waves x 4 rows = 24000 output rows
    dim3 block(256);
    geo_emb_kernel<<<grid, block, 0, stream>>>(points0, points1, out);
}